// Round 12
// baseline (240.981 us; speedup 1.0000x reference)
//
#include <hip/hip_runtime.h>

#define BB 4
#define HH 1024
#define WW 1024
#define K2 9
#define PAD 1

#define R   12            // halo radius (covers ~6 sigma offsets)
#define TW  64            // tile width (32 threads x 2 px)
#define TH  8             // tile height
#define RW  (TW + 2*R)    // 88
#define RH  (TH + 2*R)    // 32
#define RSZ (RW * RH)     // 2816 floats = 11264 B

typedef float f32x2 __attribute__((ext_vector_type(2)));

__global__ __launch_bounds__(256, 4) void dcn_kernel(
    const float* __restrict__ init_dem,   // [B,1,H,W]
    const float* __restrict__ weight,     // [B,K2,H,W]
    const float* __restrict__ offset,     // [B,2*K2,H,W]
    const float* __restrict__ wk,         // [K2]
    const float* __restrict__ bias,       // [1]
    float* __restrict__ out)              // [B,1,H,W]
{
    __shared__ float region[RSZ];

    const int HW = HH * WW;

    // batch pinned to an XCD pair (blockIdx % 8 -> XCD heuristic)
    int i    = blockIdx.x;
    int b    = (i & 7) >> 1;
    int widx = ((i >> 3) << 1) | (i & 1);     // 0 .. 2047, bijective
    int tile_w = widx & 15;                   // W/TW = 16
    int tile_h = widx >> 4;                   // H/TH = 128
    int w0 = tile_w * TW;
    int h0 = tile_h * TH;

    const float* img = init_dem + (size_t)b * HW;

    // ---- stage image region (halo included, zeros outside image) ----
    int tid = threadIdx.x;
#pragma unroll
    for (int it = 0; it < RSZ / 256; ++it) {
        int e = tid + it * 256;
        int r = e / RW;
        int c = e - r * RW;
        int gy = h0 - R + r;
        int gx = w0 - R + c;
        float v = 0.f;
        if ((unsigned)gy < (unsigned)HH && (unsigned)gx < (unsigned)WW)
            v = img[gy * WW + gx];
        region[e] = v;
    }
    __syncthreads();

    const int lx  = tid & 31;          // lane-in-row
    const int row = tid >> 5;          // 0..7
    const int h   = h0 + row;
    const int wpx = w0 + (lx << 1);    // even -> 8B aligned
    const int rem = h * WW + wpx;

    const float* wq = weight + (size_t)b * K2 * HW + rem;
    const float* oq = offset + (size_t)b * 2 * K2 * HW + rem;

    // ---- 27 dwordx2 NT stream loads, no dependent compute in the loop ----
    f32x2 wt2[K2], dy2[K2], dx2[K2];
#pragma unroll
    for (int k = 0; k < K2; ++k) {
        wt2[k] = __builtin_nontemporal_load((const f32x2*)(wq + (size_t)k * HW));
        dy2[k] = __builtin_nontemporal_load((const f32x2*)(oq + (size_t)(2 * k) * HW));
        dx2[k] = __builtin_nontemporal_load((const f32x2*)(oq + (size_t)(2 * k + 1) * HW));
    }

    const float fy = (float)(row + R - PAD);
    const float fx0 = (float)((lx << 1) + R - PAD);

    float accA[2] = {0.f, 0.f};   // sum samp*wk*wt
    float accB[2] = {0.f, 0.f};   // sum samp*wk
    float msum[2] = {0.f, 0.f};   // sum wt

#pragma unroll
    for (int k = 0; k < K2; ++k) {
        const int ky = k / 3, kx = k % 3;
        const float wkk = wk[k];
#pragma unroll
        for (int p = 0; p < 2; ++p) {
            float wt = wt2[k][p], dy = dy2[k][p], dx = dx2[k][p];
            msum[p] += wt;

            float ysl = (fy + (float)ky) + dy;
            float xsl = (fx0 + (float)(kx + p)) + dx;

            float y0f = floorf(ysl);
            float x0f = floorf(xsl);
            float wy1 = ysl - y0f;
            float wx1 = xsl - x0f;
            float wy0 = 1.f - wy1;
            float wx0 = 1.f - wx1;

            int y0l = (int)y0f;
            int x0l = (int)x0f;

            float v00, v01, v10, v11;
            if (((unsigned)y0l < (unsigned)(RH - 1)) &
                ((unsigned)x0l < (unsigned)(RW - 1))) {
                int base = y0l * RW + x0l;
                v00 = region[base];
                v10 = region[base + RW];
                v01 = region[base + 1];
                v11 = region[base + RW + 1];
            } else {
                int y0g = y0l + (h0 - R);
                int x0g = x0l + (w0 - R);
                int y1g = y0g + 1;
                int x1g = x0g + 1;
                bool y0v = (y0g >= 0) & (y0g < HH);
                bool y1v = (y1g >= 0) & (y1g < HH);
                bool x0v = (x0g >= 0) & (x0g < WW);
                bool x1v = (x1g >= 0) & (x1g < WW);
                int yc0 = min(max(y0g, 0), HH - 1);
                int yc1 = min(max(y1g, 0), HH - 1);
                int xc0 = min(max(x0g, 0), WW - 1);
                int xc1 = min(max(x1g, 0), WW - 1);
                v00 = (y0v & x0v) ? img[(size_t)yc0 * WW + xc0] : 0.f;
                v01 = (y0v & x1v) ? img[(size_t)yc0 * WW + xc1] : 0.f;
                v10 = (y1v & x0v) ? img[(size_t)yc1 * WW + xc0] : 0.f;
                v11 = (y1v & x1v) ? img[(size_t)yc1 * WW + xc1] : 0.f;
            }

            float samp = wy0 * (wx0 * v00 + wx1 * v01)
                       + wy1 * (wx0 * v10 + wx1 * v11);
            float sw = samp * wkk;
            accA[p] += sw * wt;
            accB[p] += sw;
        }
    }

    const float bval = bias[0];
    f32x2 res;
#pragma unroll
    for (int p = 0; p < 2; ++p) {
        float mean  = msum[p] * (1.0f / K2);
        float resid = region[(row + R) * RW + ((lx << 1) + p + R)];
        res[p] = accA[p] - mean * accB[p] + bval + resid;
    }
    __builtin_nontemporal_store(res, (f32x2*)(out + (size_t)b * HW + rem));
}

extern "C" void kernel_launch(void* const* d_in, const int* in_sizes, int n_in,
                              void* d_out, int out_size, void* d_ws, size_t ws_size,
                              hipStream_t stream) {
    const float* init_dem = (const float*)d_in[0];
    const float* weight   = (const float*)d_in[1];
    const float* offset   = (const float*)d_in[2];
    const float* wk       = (const float*)d_in[3];
    const float* bias     = (const float*)d_in[4];
    float* out            = (float*)d_out;

    const int nblocks = BB * (WW / TW) * (HH / TH);   // 4*16*128 = 8192
    dcn_kernel<<<dim3(nblocks), dim3(256), 0, stream>>>(init_dem, weight, offset, wk, bias, out);
}

// Round 13
// 131.774 us; speedup vs baseline: 1.8287x; 1.8287x over previous
//
#include <hip/hip_runtime.h>

#define BB 4
#define HH 1024
#define WW 1024
#define K2 9
#define PAD 1

#define R   12            // halo radius (covers ~6 sigma offsets)
#define TW  64            // tile width
#define TH  4             // tile height (1 px per thread)
#define RW  (TW + 2*R)    // 88
#define RH  (TH + 2*R)    // 28
#define RSZ (RW * RH)     // 2464 floats = 9856 B

#define NCH 27            // 9 weight + 18 offset channels
// sbuf slab layout per channel c: lane l (of the staging wave) wrote floats
// [row=l>>4][col=(l&15)*4 .. +3] at sbuf[c*256 + l*4 .. +3]
// => element (row,col) lives at sbuf[c*256 + row*64 + col]

__global__ __launch_bounds__(256) void dcn_kernel(
    const float* __restrict__ init_dem,   // [B,1,H,W]
    const float* __restrict__ weight,     // [B,K2,H,W]
    const float* __restrict__ offset,     // [B,2*K2,H,W]
    const float* __restrict__ wk,         // [K2]
    const float* __restrict__ bias,       // [1]
    float* __restrict__ out)              // [B,1,H,W]
{
    __shared__ float region[RSZ];
    __shared__ float sbuf[NCH * 256];     // 27648 B; total LDS 37504 B

    const int HW = HH * WW;

    // batch pinned to an XCD pair (blockIdx % 8 -> XCD heuristic)
    int i    = blockIdx.x;
    int b    = (i & 7) >> 1;
    int widx = ((i >> 3) << 1) | (i & 1);     // 0 .. 4095, bijective
    int tile_w = widx & 15;                   // W/TW = 16
    int tile_h = widx >> 4;                   // H/TH = 256
    int w0 = tile_w * TW;
    int h0 = tile_h * TH;

    const float* img = init_dem + (size_t)b * HW;

    const int tid = threadIdx.x;
    const int wv  = tid >> 6;          // wave 0..3
    const int ln  = tid & 63;          // lane
    const int srow = ln >> 4;          // staging row 0..3
    const int scol = (ln & 15) << 2;   // staging col 0,4,...,60

    // ---- cooperative stream staging: 27 slabs, wave-strided, 16B DMA ----
    const float* wslab = weight + (size_t)b * K2 * HW     + (size_t)h0 * WW + w0;
    const float* oslab = offset + (size_t)b * 2 * K2 * HW + (size_t)h0 * WW + w0;
#pragma unroll
    for (int it = 0; it < 7; ++it) {
        int c = wv + (it << 2);                 // wave-uniform channel id
        if (c < NCH) {
            const float* g = (c < 9) ? (wslab + (size_t)c * HW)
                                     : (oslab + (size_t)(c - 9) * HW);
            g += srow * WW + scol;              // per-lane global address
            // wave-uniform LDS base; HW scatters lane l -> base + l*16 bytes
            __builtin_amdgcn_global_load_lds(
                (const __attribute__((address_space(1))) void*)g,
                (__attribute__((address_space(3))) void*)&sbuf[c * 256],
                16, 0, 0);
        }
    }

    // ---- stage image region (halo included, zeros outside image) ----
#pragma unroll
    for (int it = 0; it < (RSZ + 255) / 256; ++it) {
        int e = tid + it * 256;
        if (e < RSZ) {
            int r = e / RW;
            int c = e - r * RW;
            int gy = h0 - R + r;
            int gx = w0 - R + c;
            float v = 0.f;
            if ((unsigned)gy < (unsigned)HH && (unsigned)gx < (unsigned)WW)
                v = img[gy * WW + gx];
            region[e] = v;
        }
    }
    __syncthreads();   // drains vmcnt: DMAs + region staging complete

    // ---- per-pixel compute, all inputs now in LDS ----
    const int prow = tid >> 6;         // 0..3
    const int pcol = tid & 63;
    const int h    = h0 + prow;
    const int w    = w0 + pcol;
    const int rem  = h * WW + w;
    const int sidx = prow * 64 + pcol; // within-slab float index

    float wt[K2];
    float wsum = 0.f;
#pragma unroll
    for (int k = 0; k < K2; ++k) {
        wt[k] = sbuf[k * 256 + sidx];
        wsum += wt[k];
    }
    const float mean = wsum * (1.0f / K2);
    const float bval = bias[0];

    const float fy = (float)(prow + R - PAD);
    const float fx = (float)(pcol + R - PAD);

    float acc = 0.f;
#pragma unroll
    for (int k = 0; k < K2; ++k) {
        const int ky = k / 3, kx = k % 3;

        float dy = sbuf[(9 + 2 * k)  * 256 + sidx];
        float dx = sbuf[(10 + 2 * k) * 256 + sidx];

        float ysl = (fy + (float)ky) + dy;
        float xsl = (fx + (float)kx) + dx;

        float y0f = floorf(ysl);
        float x0f = floorf(xsl);
        float wy1 = ysl - y0f;
        float wx1 = xsl - x0f;
        float wy0 = 1.f - wy1;
        float wx0 = 1.f - wx1;

        int y0l = (int)y0f;
        int x0l = (int)x0f;

        float v00, v01, v10, v11;
        if (((unsigned)y0l < (unsigned)(RH - 1)) &
            ((unsigned)x0l < (unsigned)(RW - 1))) {
            int base = y0l * RW + x0l;
            v00 = region[base];
            v10 = region[base + RW];
            v01 = region[base + 1];
            v11 = region[base + RW + 1];
        } else {
            int y0g = y0l + (h0 - R);
            int x0g = x0l + (w0 - R);
            int y1g = y0g + 1;
            int x1g = x0g + 1;
            bool y0v = (y0g >= 0) & (y0g < HH);
            bool y1v = (y1g >= 0) & (y1g < HH);
            bool x0v = (x0g >= 0) & (x0g < WW);
            bool x1v = (x1g >= 0) & (x1g < WW);
            int yc0 = min(max(y0g, 0), HH - 1);
            int yc1 = min(max(y1g, 0), HH - 1);
            int xc0 = min(max(x0g, 0), WW - 1);
            int xc1 = min(max(x1g, 0), WW - 1);
            v00 = (y0v & x0v) ? img[(size_t)yc0 * WW + xc0] : 0.f;
            v01 = (y0v & x1v) ? img[(size_t)yc0 * WW + xc1] : 0.f;
            v10 = (y1v & x0v) ? img[(size_t)yc1 * WW + xc0] : 0.f;
            v11 = (y1v & x1v) ? img[(size_t)yc1 * WW + xc1] : 0.f;
        }

        float samp = wy0 * (wx0 * v00 + wx1 * v01)
                   + wy1 * (wx0 * v10 + wx1 * v11);
        acc += samp * (wt[k] - mean) * wk[k];
    }

    float resid = region[(prow + R) * RW + (pcol + R)];
    float rres  = acc + bval + resid;
    __builtin_nontemporal_store(rres, out + (size_t)b * HW + rem);
}

extern "C" void kernel_launch(void* const* d_in, const int* in_sizes, int n_in,
                              void* d_out, int out_size, void* d_ws, size_t ws_size,
                              hipStream_t stream) {
    const float* init_dem = (const float*)d_in[0];
    const float* weight   = (const float*)d_in[1];
    const float* offset   = (const float*)d_in[2];
    const float* wk       = (const float*)d_in[3];
    const float* bias     = (const float*)d_in[4];
    float* out            = (float*)d_out;

    const int nblocks = BB * (WW / TW) * (HH / TH);   // 4*16*256 = 16384
    dcn_kernel<<<dim3(nblocks), dim3(256), 0, stream>>>(init_dem, weight, offset, wk, bias, out);
}

// Round 14
// 121.171 us; speedup vs baseline: 1.9888x; 1.0875x over previous
//
#include <hip/hip_runtime.h>

#define BB 4
#define HH 1024
#define WW 1024
#define K2 9
#define PAD 1

#define R   12            // halo radius (covers ~6 sigma offsets)
#define TW  64            // tile width
#define STH 4             // sub-tile height (1 px per thread per sub-tile)
#define TH  8             // super-tile height = 2 sub-tiles
#define RW  (TW + 2*R)    // 88
#define RH  (TH + 2*R)    // 32
#define RSZ (RW * RH)     // 2816 floats = 11264 B

#define NOCH 18           // offset channels (dy,dx interleaved)
// slab layout, channel c, sub-tile s: element (row,col) of the 4x64 slab
// lives at sbuf[s][c*256 + row*64 + col]  (lane l DMAs floats l*4..l*4+3)

__global__ __launch_bounds__(256) void dcn_kernel(
    const float* __restrict__ init_dem,   // [B,1,H,W]
    const float* __restrict__ weight,     // [B,K2,H,W]
    const float* __restrict__ offset,     // [B,2*K2,H,W]
    const float* __restrict__ wk,         // [K2]
    const float* __restrict__ bias,       // [1]
    float* __restrict__ out)              // [B,1,H,W]
{
    __shared__ float region[RSZ];
    __shared__ float sbuf[2][NOCH * 256];   // 36864 B; total LDS 48128 B

    const int HW = HH * WW;

    // batch pinned to an XCD pair (blockIdx % 8 -> XCD heuristic)
    int i    = blockIdx.x;
    int b    = (i & 7) >> 1;
    int widx = ((i >> 3) << 1) | (i & 1);     // 0 .. 2047, bijective
    int tile_w = widx & 15;                   // W/TW = 16
    int tile_h = widx >> 4;                   // H/TH = 128
    int w0 = tile_w * TW;
    int h0 = tile_h * TH;

    const float* img = init_dem + (size_t)b * HW;

    const int tid  = threadIdx.x;
    const int wv   = tid >> 6;         // wave 0..3
    const int ln   = tid & 63;
    const int srow = ln >> 4;          // DMA row 0..3
    const int scol = (ln & 15) << 2;   // DMA col 0,4,...,60

    const int prow = wv;               // pixel row within sub-tile
    const int pcol = ln;               // pixel col
    const int rem0 = (h0 + prow) * WW + w0 + pcol;
    const int rem1 = rem0 + STH * WW;

    // ---- 1) per-thread wt loads for BOTH sub-tiles (issued first) ----
    const float* wq = weight + (size_t)b * K2 * HW;
    float wt0[K2], wt1[K2];
#pragma unroll
    for (int k = 0; k < K2; ++k) {
        wt0[k] = __builtin_nontemporal_load(wq + (size_t)k * HW + rem0);
        wt1[k] = __builtin_nontemporal_load(wq + (size_t)k * HW + rem1);
    }

    // ---- 2) cooperative DMA of all 36 offset slabs (wave-uniform dest) ----
    const float* ob = offset + (size_t)b * 2 * K2 * HW + (size_t)h0 * WW + w0;
#pragma unroll
    for (int it = 0; it < 5; ++it) {
        int c = wv + (it << 2);                 // wave-uniform channel id
        if (c < NOCH) {
            const float* g0 = ob + (size_t)c * HW + srow * WW + scol;
            __builtin_amdgcn_global_load_lds(
                (const __attribute__((address_space(1))) void*)g0,
                (__attribute__((address_space(3))) void*)&sbuf[0][c * 256],
                16, 0, 0);
            __builtin_amdgcn_global_load_lds(
                (const __attribute__((address_space(1))) void*)(g0 + STH * WW),
                (__attribute__((address_space(3))) void*)&sbuf[1][c * 256],
                16, 0, 0);
        }
    }

    // ---- 3) stage image region (latency-hiding window for 1) and 2)) ----
#pragma unroll
    for (int it = 0; it < RSZ / 256; ++it) {
        int e = tid + it * 256;
        int r = e / RW;
        int c = e - r * RW;
        int gy = h0 - R + r;
        int gx = w0 - R + c;
        float v = 0.f;
        if ((unsigned)gy < (unsigned)HH && (unsigned)gx < (unsigned)WW)
            v = img[gy * WW + gx];
        region[e] = v;
    }
    __syncthreads();   // drains vmcnt: wt, DMAs, region all complete

    const float bval = bias[0];
    const int   sidx = prow * 64 + pcol;
    const float fx   = (float)(pcol + R - PAD);

#pragma unroll
    for (int s = 0; s < 2; ++s) {
        const float* wts = s ? wt1 : wt0;
        const int    rem = s ? rem1 : rem0;
        const float  fy  = (float)(prow + s * STH + R - PAD);

        float wsum = 0.f;
#pragma unroll
        for (int k = 0; k < K2; ++k) wsum += wts[k];
        const float mean = wsum * (1.0f / K2);

        float acc = 0.f;
#pragma unroll
        for (int k = 0; k < K2; ++k) {
            const int ky = k / 3, kx = k % 3;

            float dy = sbuf[s][(2 * k)     * 256 + sidx];
            float dx = sbuf[s][(2 * k + 1) * 256 + sidx];

            float ysl = (fy + (float)ky) + dy;
            float xsl = (fx + (float)kx) + dx;

            float y0f = floorf(ysl);
            float x0f = floorf(xsl);
            float wy1 = ysl - y0f;
            float wx1 = xsl - x0f;
            float wy0 = 1.f - wy1;
            float wx0 = 1.f - wx1;

            int y0l = (int)y0f;
            int x0l = (int)x0f;

            float v00, v01, v10, v11;
            if (((unsigned)y0l < (unsigned)(RH - 1)) &
                ((unsigned)x0l < (unsigned)(RW - 1))) {
                int base = y0l * RW + x0l;
                v00 = region[base];
                v10 = region[base + RW];
                v01 = region[base + 1];
                v11 = region[base + RW + 1];
            } else {
                int y0g = y0l + (h0 - R);
                int x0g = x0l + (w0 - R);
                int y1g = y0g + 1;
                int x1g = x0g + 1;
                bool y0v = (y0g >= 0) & (y0g < HH);
                bool y1v = (y1g >= 0) & (y1g < HH);
                bool x0v = (x0g >= 0) & (x0g < WW);
                bool x1v = (x1g >= 0) & (x1g < WW);
                int yc0 = min(max(y0g, 0), HH - 1);
                int yc1 = min(max(y1g, 0), HH - 1);
                int xc0 = min(max(x0g, 0), WW - 1);
                int xc1 = min(max(x1g, 0), WW - 1);
                v00 = (y0v & x0v) ? img[(size_t)yc0 * WW + xc0] : 0.f;
                v01 = (y0v & x1v) ? img[(size_t)yc0 * WW + xc1] : 0.f;
                v10 = (y1v & x0v) ? img[(size_t)yc1 * WW + xc0] : 0.f;
                v11 = (y1v & x1v) ? img[(size_t)yc1 * WW + xc1] : 0.f;
            }

            float samp = wy0 * (wx0 * v00 + wx1 * v01)
                       + wy1 * (wx0 * v10 + wx1 * v11);
            acc += samp * (wts[k] - mean) * wk[k];
        }

        float resid = region[(prow + s * STH + R) * RW + (pcol + R)];
        float rres  = acc + bval + resid;
        __builtin_nontemporal_store(rres, out + (size_t)b * HW + rem);
    }
}

extern "C" void kernel_launch(void* const* d_in, const int* in_sizes, int n_in,
                              void* d_out, int out_size, void* d_ws, size_t ws_size,
                              hipStream_t stream) {
    const float* init_dem = (const float*)d_in[0];
    const float* weight   = (const float*)d_in[1];
    const float* offset   = (const float*)d_in[2];
    const float* wk       = (const float*)d_in[3];
    const float* bias     = (const float*)d_in[4];
    float* out            = (float*)d_out;

    const int nblocks = BB * (WW / TW) * (HH / TH);   // 4*16*128 = 8192
    dcn_kernel<<<dim3(nblocks), dim3(256), 0, stream>>>(init_dem, weight, offset, wk, bias, out);
}